// Round 19
// baseline (121.856 us; speedup 1.0000x reference)
//
#include <hip/hip_runtime.h>

#define E_EDGES 8192
#define N_COMP  20000
#define N_IND   500
#define NKEYS   512

typedef short bf16x8 __attribute__((ext_vector_type(8)));
typedef float f32x4  __attribute__((ext_vector_type(4)));

static __device__ __forceinline__ unsigned short f2bf(float v) {
    unsigned u = __builtin_bit_cast(unsigned, v);
    u = (u + 0x7FFFu + ((u >> 16) & 1u)) >> 16;
    return (unsigned short)u;
}

static __device__ __forceinline__ void cvt8(const float* __restrict__ s,
                                            unsigned short* __restrict__ d) {
    float4 a = *(const float4*)s;
    float4 b = *(const float4*)(s + 4);
    bf16x8 o;
    o[0] = (short)f2bf(a.x); o[1] = (short)f2bf(a.y);
    o[2] = (short)f2bf(a.z); o[3] = (short)f2bf(a.w);
    o[4] = (short)f2bf(b.x); o[5] = (short)f2bf(b.y);
    o[6] = (short)f2bf(b.z); o[7] = (short)f2bf(b.w);
    *(bf16x8*)d = o;
}

static __device__ __forceinline__ bf16x8 cvt8r(const float* __restrict__ s) {
    float4 a = *(const float4*)s;
    float4 b = *(const float4*)(s + 4);
    bf16x8 v;
    v[0] = (short)f2bf(a.x); v[1] = (short)f2bf(a.y);
    v[2] = (short)f2bf(a.z); v[3] = (short)f2bf(a.w);
    v[4] = (short)f2bf(b.x); v[5] = (short)f2bf(b.y);
    v[6] = (short)f2bf(b.z); v[7] = (short)f2bf(b.w);
    return v;
}

#define SWZ(r)   (((r) & 7) << 4)
#define SWZ4(r)  ((((r) >> 1) & 3) << 4)

static __device__ __forceinline__ void stage_f32(const float* src, char* base,
                                                 int sr, int sc) {
    *(bf16x8*)(base + ((sr * 64 + sc * 2) ^ SWZ(sr))) = cvt8r(src);
}

// ---------------------------------------------------------------------------
// prep (unchanged, known-good).
// ---------------------------------------------------------------------------
__global__ __launch_bounds__(256) void prep(
    const int* __restrict__ src, const int* __restrict__ tgt,
    const float* __restrict__ Wc, const float* __restrict__ Wi,
    const float* __restrict__ w_out, const float* __restrict__ w_in,
    const float* __restrict__ bc, const float* __restrict__ bi,
    const float* __restrict__ b_in,
    float* __restrict__ csrc, float* __restrict__ ctgt,
    unsigned short* __restrict__ Wc_bf, unsigned short* __restrict__ wout_bf,
    unsigned short* __restrict__ WcT_bf, unsigned short* __restrict__ Wi_bf,
    unsigned short* __restrict__ wkv_bf, float* __restrict__ beff)
{
    const int bid = blockIdx.x, tid = threadIdx.x;
    if (bid < 32) {
        int e = bid * 256 + tid;
        atomicAdd(&csrc[src[e]], 1.0f);
        atomicAdd(&ctgt[tgt[e]], 1.0f);
    } else if (bid < 64) {
        long i = ((long)(bid - 32) * 256 + tid) * 8;
        cvt8(Wc + i, Wc_bf + i);
    } else if (bid < 96) {
        long i = ((long)(bid - 64) * 256 + tid) * 8;
        cvt8(w_out + i, wout_bf + i);
    } else if (bid < 128) {
        long o = ((long)(bid - 96) * 256 + tid) * 8;
        int c = (int)(o >> 8), d0 = (int)(o & 255);
        bf16x8 v;
#pragma unroll
        for (int j = 0; j < 8; j++) v[j] = (short)f2bf(Wc[(long)(d0 + j) * 256 + c]);
        *(bf16x8*)(WcT_bf + o) = v;
    } else if (bid < 144) {
        long i = ((long)(bid - 128) * 256 + tid) * 8;
        cvt8(Wi + i, Wi_bf + i);
    } else if (bid < 208) {
        long i = ((long)(bid - 144) * 256 + tid) * 8;
        cvt8(w_in + 65536 + i, wkv_bf + i);
    } else {
        int gi = (bid - 208) * 256 + tid;      // [0, 3072)
        int e = gi >> 2, q = gi & 3;
        const float* base = (e < 256) ? bc : bi;
        const float* wr = w_in + (long)e * 256 + q * 64;
        const float* br = base + q * 64;
        float s = 0.f;
#pragma unroll
        for (int j = 0; j < 64; j += 4) {
            float4 w4 = *(const float4*)(wr + j);
            float4 b4 = *(const float4*)(br + j);
            s += w4.x * b4.x + w4.y * b4.y + w4.z * b4.z + w4.w * b4.w;
        }
        s += __shfl_xor(s, 1);
        s += __shfl_xor(s, 2);
        if (q == 0) beff[e] = s + b_in[e];
    }
}

// ---------------------------------------------------------------------------
// fusedW (LDS-staged; unchanged, known-good).
// ---------------------------------------------------------------------------
__global__ __launch_bounds__(256) void fusedW(
    const float* __restrict__ w_in, const unsigned short* __restrict__ WcT_bf,
    const float* __restrict__ industry_x, const unsigned short* __restrict__ Wi_bf,
    const unsigned short* __restrict__ wkv_bf, const float* __restrict__ beff,
    const float* __restrict__ ctgt, const float* __restrict__ csrc,
    unsigned short* __restrict__ Wcq_bf, unsigned short* __restrict__ Kbuf,
    unsigned short* __restrict__ VTg,
    float* __restrict__ cntT, int* __restrict__ list, int* __restrict__ nlist)
{
    const int bid = blockIdx.x;
    if (bid >= 20) {
        int i = (bid - 20) * 256 + threadIdx.x;
        if (i < NKEYS) cntT[(i & 15) * 32 + (i >> 4)] = ctgt[i];
        if (i < N_COMP && csrc[i] > 0.f) {
            int k = atomicAdd(nlist, 1);
            list[k] = i;
        }
        return;
    }

    __shared__ char lds[48 * 1024];
    const int t = threadIdx.x, wv = t >> 6, lane = t & 63;
    const int g = lane >> 4, ln = lane & 15;
    const int sr = t >> 2, sc = (t & 3) * 8;

    if (bid < 4) {
        char* ab = lds;
        char* wb = lds + 4 * 1024;
        const int bm = bid * 64;
        f32x4 acc[16];
#pragma unroll
        for (int i = 0; i < 16; i++) acc[i] = (f32x4){0.f, 0.f, 0.f, 0.f};
        const float* aptr = w_in + (long)(bm + sr) * 256 + sc;
        for (int kc = 0; kc < 256; kc += 32) {
            __syncthreads();
            stage_f32(aptr + kc, ab, sr, sc);
#pragma unroll
            for (int p = 0; p < 4; p++) {
                int r = p * 64 + sr;
                *(bf16x8*)(wb + ((r * 64 + sc * 2) ^ SWZ(r))) =
                    *(const bf16x8*)(WcT_bf + (long)r * 256 + kc + sc);
            }
            __syncthreads();
            int ar = wv * 16 + ln;
            bf16x8 af = *(bf16x8*)(ab + ((ar * 64 + g * 16) ^ SWZ(ar)));
#pragma unroll
            for (int nj = 0; nj < 16; nj++) {
                int wr = nj * 16 + ln;
                bf16x8 bf = *(bf16x8*)(wb + ((wr * 64 + g * 16) ^ SWZ(wr)));
                acc[nj] = __builtin_amdgcn_mfma_f32_16x16x32_bf16(af, bf, acc[nj], 0, 0, 0);
            }
        }
#pragma unroll
        for (int nj = 0; nj < 16; nj++)
#pragma unroll
            for (int r = 0; r < 4; r++)
                Wcq_bf[(long)(bm + wv * 16 + g * 4 + r) * 256 + nj * 16 + ln] =
                    f2bf(acc[nj][r]);
        return;
    }

    const int rg = (bid - 4) >> 1, colh = (bid - 4) & 1;
    char* ab  = lds;
    char* wb1 = lds + 4 * 1024;
    char* ihb = lds + 16 * 1024;
    char* wb2 = lds;

    {
        f32x4 a1[16];
#pragma unroll
        for (int i = 0; i < 16; i++) a1[i] = (f32x4){0.f, 0.f, 0.f, 0.f};
        int arow = rg * 64 + sr; if (arow > N_IND - 1) arow = N_IND - 1;
        const float* aptr = industry_x + (long)arow * 128 + sc;
        for (int kc = 0; kc < 128; kc += 32) {
            __syncthreads();
            stage_f32(aptr + kc, ab, sr, sc);
#pragma unroll
            for (int p = 0; p < 4; p++) {
                int r = p * 64 + sr;
                *(bf16x8*)(wb1 + ((r * 64 + sc * 2) ^ SWZ(r))) =
                    *(const bf16x8*)(Wi_bf + (long)r * 128 + kc + sc);
            }
            __syncthreads();
            int ar = wv * 16 + ln;
            bf16x8 af = *(bf16x8*)(ab + ((ar * 64 + g * 16) ^ SWZ(ar)));
#pragma unroll
            for (int nj = 0; nj < 16; nj++) {
                int wr = nj * 16 + ln;
                bf16x8 bf = *(bf16x8*)(wb1 + ((wr * 64 + g * 16) ^ SWZ(wr)));
                a1[nj] = __builtin_amdgcn_mfma_f32_16x16x32_bf16(af, bf, a1[nj], 0, 0, 0);
            }
        }
        __syncthreads();
#pragma unroll
        for (int nj = 0; nj < 16; nj++)
#pragma unroll
            for (int r = 0; r < 4; r++) {
                int row = wv * 16 + g * 4 + r, col = nj * 16 + ln;
                *(unsigned short*)(ihb + ((row * 512 + col * 2) ^ SWZ(row))) =
                    f2bf(a1[nj][r]);
            }
    }
    __syncthreads();

    if (colh == 0) {
        f32x4 a2[16];
#pragma unroll
        for (int i = 0; i < 16; i++) a2[i] = (f32x4){0.f, 0.f, 0.f, 0.f};
        for (int kc = 0; kc < 256; kc += 32) {
            __syncthreads();
#pragma unroll
            for (int p = 0; p < 4; p++) {
                int r = p * 64 + sr;
                *(bf16x8*)(wb2 + ((r * 64 + sc * 2) ^ SWZ(r))) =
                    *(const bf16x8*)(wkv_bf + (long)r * 256 + kc + sc);
            }
            __syncthreads();
            int row = wv * 16 + ln;
            bf16x8 af = *(bf16x8*)(ihb + ((row * 512 + (kc + g * 8) * 2) ^ SWZ(row)));
#pragma unroll
            for (int nj = 0; nj < 16; nj++) {
                int wr = nj * 16 + ln;
                bf16x8 bf = *(bf16x8*)(wb2 + ((wr * 64 + g * 16) ^ SWZ(wr)));
                a2[nj] = __builtin_amdgcn_mfma_f32_16x16x32_bf16(af, bf, a2[nj], 0, 0, 0);
            }
        }
#pragma unroll
        for (int nj = 0; nj < 16; nj++)
#pragma unroll
            for (int r = 0; r < 4; r++) {
                int R = rg * 64 + wv * 16 + g * 4 + r, n = nj * 16 + ln;
                Kbuf[(long)R * 256 + n] = f2bf(a2[nj][r] + beff[256 + n]);
            }
    } else {
        const unsigned short* wp = wkv_bf + 65536;
        f32x4 a2[16];
#pragma unroll
        for (int i = 0; i < 16; i++) a2[i] = (f32x4){0.f, 0.f, 0.f, 0.f};
        for (int kc = 0; kc < 256; kc += 32) {
            __syncthreads();
#pragma unroll
            for (int p = 0; p < 4; p++) {
                int r = p * 64 + sr;
                *(bf16x8*)(wb2 + ((r * 64 + sc * 2) ^ SWZ(r))) =
                    *(const bf16x8*)(wp + (long)r * 256 + kc + sc);
            }
            __syncthreads();
#pragma unroll
            for (int mi = 0; mi < 4; mi++) {
                int arow = wv * 64 + mi * 16 + ln;
                bf16x8 af = *(bf16x8*)(wb2 + ((arow * 64 + g * 16) ^ SWZ(arow)));
#pragma unroll
                for (int t4 = 0; t4 < 4; t4++) {
                    int brow = t4 * 16 + ln;
                    bf16x8 bfr = *(bf16x8*)(ihb + ((brow * 512 + (kc + g * 8) * 2) ^ SWZ(brow)));
                    a2[mi * 4 + t4] = __builtin_amdgcn_mfma_f32_16x16x32_bf16(af, bfr, a2[mi * 4 + t4], 0, 0, 0);
                }
            }
        }
#pragma unroll
        for (int mi = 0; mi < 4; mi++)
#pragma unroll
            for (int t4 = 0; t4 < 4; t4++)
#pragma unroll
                for (int r = 0; r < 4; r++) {
                    int nrow = wv * 64 + mi * 16 + g * 4 + r;
                    VTg[(long)nrow * 512 + rg * 64 + t4 * 16 + ln] =
                        f2bf(a2[mi * 4 + t4][r] + beff[512 + nrow]);
                }
    }
}

// ---------------------------------------------------------------------------
// qproj (unchanged, known-good).
// ---------------------------------------------------------------------------
__global__ __launch_bounds__(256) void qproj(
    const float* __restrict__ company_x, const int* __restrict__ list,
    const int* __restrict__ nlist, const unsigned short* __restrict__ Wcq,
    const float* __restrict__ beff, unsigned short* __restrict__ Qb)
{
    const int M = *nlist;
    const int bm = blockIdx.x * 64;
    if (bm >= M) return;

    __shared__ unsigned short As[64 * 32];
    __shared__ unsigned short Ws[256 * 32];
    char* abase = (char*)As;
    char* wbase = (char*)Ws;

    const int t = threadIdx.x;
    const int wv = t >> 6, lane = t & 63, g = lane >> 4, ln = lane & 15;

    f32x4 acc[16];
#pragma unroll
    for (int i = 0; i < 16; i++) acc[i] = (f32x4){0.f, 0.f, 0.f, 0.f};

    const int sr = t >> 2;
    const int sc = (t & 3) * 8;
    int mrow = bm + sr; if (mrow > M - 1) mrow = M - 1;
    const float* aptr = company_x + (long)list[mrow] * 256 + sc;

    for (int kc = 0; kc < 256; kc += 32) {
        __syncthreads();
        stage_f32(aptr + kc, abase, sr, sc);
#pragma unroll
        for (int p = 0; p < 4; p++) {
            int r = p * 64 + sr;
            *(bf16x8*)(wbase + ((r * 64 + sc * 2) ^ SWZ(r))) =
                *(const bf16x8*)(Wcq + (long)r * 256 + kc + sc);
        }
        __syncthreads();
        const int ar = wv * 16 + ln;
        bf16x8 af = *(bf16x8*)(abase + ((ar * 64 + g * 16) ^ SWZ(ar)));
#pragma unroll
        for (int nj = 0; nj < 16; nj++) {
            int wr = nj * 16 + ln;
            bf16x8 bf = *(bf16x8*)(wbase + ((wr * 64 + g * 16) ^ SWZ(wr)));
            acc[nj] = __builtin_amdgcn_mfma_f32_16x16x32_bf16(af, bf, acc[nj], 0, 0, 0);
        }
    }
#pragma unroll
    for (int nj = 0; nj < 16; nj++) {
        int n = nj * 16 + ln;
        float bv = beff[n];
#pragma unroll
        for (int r = 0; r < 4; r++) {
            int m = bm + wv * 16 + g * 4 + r;
            if (m < M)
                Qb[(long)m * 256 + n] = f2bf((acc[nj][r] + bv) * 0.125f);
        }
    }
}

// ---------------------------------------------------------------------------
// megattn v9 (round-17 measured 40.1 us) — bare attention chain, but ctx
// written COMPACT (out_proj gathers by row index directly).
// ---------------------------------------------------------------------------
__global__ __launch_bounds__(256) void megattn(
    const unsigned short* __restrict__ Qb,
    const unsigned short* __restrict__ Kbuf,
    const unsigned short* __restrict__ VTg,
    const float* __restrict__ cntT,
    const int* __restrict__ nlist,
    unsigned short* __restrict__ ctx)
{
    const int M = *nlist;
    const int bm = blockIdx.x * 16;
    if (bm >= M) return;

    __shared__ char lds[16384];
    const int t = threadIdx.x, h = t >> 6, lane = t & 63;
    const int g = lane >> 4, ln = lane & 15;
    char* pbase = lds + h * 4096;   // per-wave P 4-slot buffer

    bf16x8 qf0, qf1;
    {
        int qrow = bm + ln; if (qrow > M - 1) qrow = M - 1;
        const unsigned short* qp = Qb + (long)qrow * 256 + h * 64 + g * 8;
        qf0 = *(const bf16x8*)(qp);
        qf1 = *(const bf16x8*)(qp + 32);
    }

    f32x4 acc[4];
#pragma unroll
    for (int i = 0; i < 4; i++) acc[i] = (f32x4){0.f, 0.f, 0.f, 0.f};
    float mreg[4] = {-1e30f, -1e30f, -1e30f, -1e30f};
    float lreg[4] = {0.f, 0.f, 0.f, 0.f};

#pragma unroll
    for (int tile = 0; tile < 2; tile++) {
        float cnt[16];
        {
            const float* cp = cntT + ln * 32 + tile * 16;
#pragma unroll
            for (int j4 = 0; j4 < 4; j4++) {
                float4 c4 = *(const float4*)(cp + j4 * 4);
                cnt[j4 * 4 + 0] = c4.x; cnt[j4 * 4 + 1] = c4.y;
                cnt[j4 * 4 + 2] = c4.z; cnt[j4 * 4 + 3] = c4.w;
            }
        }

        f32x4 S[8][2];
#pragma unroll
        for (int half = 0; half < 2; half++) {
            bf16x8 k0r[4][2], k1r[4][2];
#pragma unroll
            for (int c4 = 0; c4 < 4; c4++)
#pragma unroll
                for (int sub = 0; sub < 2; sub++) {
                    const unsigned short* kr = Kbuf +
                        (long)(tile * 256 + (half * 4 + c4) * 32 + sub * 16 + ln) * 256 + h * 64 + g * 8;
                    k0r[c4][sub] = *(const bf16x8*)(kr);
                    k1r[c4][sub] = *(const bf16x8*)(kr + 32);
                }
#pragma unroll
            for (int c4 = 0; c4 < 4; c4++)
#pragma unroll
                for (int sub = 0; sub < 2; sub++) {
                    f32x4 s = (f32x4){0.f, 0.f, 0.f, 0.f};
                    s = __builtin_amdgcn_mfma_f32_16x16x32_bf16(qf0, k0r[c4][sub], s, 0, 0, 0);
                    s = __builtin_amdgcn_mfma_f32_16x16x32_bf16(qf1, k1r[c4][sub], s, 0, 0, 0);
                    S[half * 4 + c4][sub] = s;
                }
        }

        bf16x8 vr[2][2][4];
#pragma unroll
        for (int j = 0; j < 2; j++)
#pragma unroll
            for (int t4 = 0; t4 < 4; t4++)
                vr[0][j][t4] = *(const bf16x8*)(
                    VTg + (long)(h * 64 + t4 * 16 + ln) * 512 + tile * 256 + j * 32 + g * 8);

        float tm[4] = {-1e30f, -1e30f, -1e30f, -1e30f};
#pragma unroll
        for (int c = 0; c < 8; c++)
#pragma unroll
            for (int sub = 0; sub < 2; sub++)
#pragma unroll
                for (int r = 0; r < 4; r++) tm[r] = fmaxf(tm[r], S[c][sub][r]);
#pragma unroll
        for (int st = 1; st < 16; st <<= 1)
#pragma unroll
            for (int r = 0; r < 4; r++) tm[r] = fmaxf(tm[r], __shfl_xor(tm[r], st));

        float corr[4];
#pragma unroll
        for (int r = 0; r < 4; r++) {
            float mn = fmaxf(mreg[r], tm[r]);
            corr[r] = __expf(mreg[r] - mn);
            mreg[r] = mn;
        }

        float ps[4] = {0.f, 0.f, 0.f, 0.f};
#pragma unroll
        for (int c = 0; c < 8; c++)
#pragma unroll
            for (int sub = 0; sub < 2; sub++) {
                float cv = cnt[c * 2 + sub];
#pragma unroll
                for (int r = 0; r < 4; r++) {
                    float p = cv * __expf(S[c][sub][r] - mreg[r]);
                    S[c][sub][r] = p;
                    ps[r] += p;
                }
            }
#pragma unroll
        for (int st = 1; st < 16; st <<= 1)
#pragma unroll
            for (int r = 0; r < 4; r++) ps[r] += __shfl_xor(ps[r], st);
#pragma unroll
        for (int r = 0; r < 4; r++) lreg[r] = lreg[r] * corr[r] + ps[r];
#pragma unroll
        for (int i = 0; i < 4; i++)
#pragma unroll
            for (int r = 0; r < 4; r++) acc[i][r] *= corr[r];

#pragma unroll
        for (int grp = 0; grp < 4; grp++) {
            if (grp < 3) {
#pragma unroll
                for (int j = 0; j < 2; j++)
#pragma unroll
                    for (int t4 = 0; t4 < 4; t4++)
                        vr[(grp + 1) & 1][j][t4] = *(const bf16x8*)(
                            VTg + (long)(h * 64 + t4 * 16 + ln) * 512 +
                            tile * 256 + ((grp + 1) * 2 + j) * 32 + g * 8);
            }
#pragma unroll
            for (int j = 0; j < 2; j++) {
                int c = grp * 2 + j;
                char* pb = pbase + (c & 3) * 1024;
#pragma unroll
                for (int sub = 0; sub < 2; sub++)
#pragma unroll
                    for (int r = 0; r < 4; r++) {
                        int row = g * 4 + r;
                        *(unsigned short*)(pb + ((row * 64 + (sub * 16 + ln) * 2) ^ SWZ4(row))) =
                            f2bf(S[c][sub][r]);
                    }
                bf16x8 pa = *(bf16x8*)(pb + ((ln * 64 + g * 16) ^ SWZ4(ln)));
#pragma unroll
                for (int t4 = 0; t4 < 4; t4++)
                    acc[t4] = __builtin_amdgcn_mfma_f32_16x16x32_bf16(
                        pa, vr[grp & 1][j][t4], acc[t4], 0, 0, 0);
            }
        }
    }

    // compact ctx write (bf16)
#pragma unroll
    for (int r = 0; r < 4; r++) {
        int R = bm + g * 4 + r;
        if (R < M) {
            long base = (long)R * 256 + h * 64;
#pragma unroll
            for (int t4 = 0; t4 < 4; t4++)
                ctx[base + t4 * 16 + ln] = f2bf(acc[t4][r] / lreg[r]);
        }
    }
}

// ---------------------------------------------------------------------------
// out_proj (round-16 structure): pooled[list[R]] = ctx[R] @ wout^T + b_out.
// Barrier-free, no LDS; A-frags from compact ctx, B from L2-hot wout.
// ---------------------------------------------------------------------------
__global__ __launch_bounds__(256) void out_proj(
    const unsigned short* __restrict__ ctx,
    const unsigned short* __restrict__ wout, const float* __restrict__ b_out,
    const int* __restrict__ list, const int* __restrict__ nlist,
    float* __restrict__ pooled)
{
    const int M = *nlist;
    const int bm = blockIdx.x * 16;
    if (bm >= M) return;
    const int t = threadIdx.x, h = t >> 6, lane = t & 63;
    const int g = lane >> 4, ln = lane & 15;

    int arow = bm + ln; if (arow > M - 1) arow = M - 1;

    f32x4 oa[4];
#pragma unroll
    for (int i = 0; i < 4; i++) oa[i] = (f32x4){0.f, 0.f, 0.f, 0.f};
#pragma unroll
    for (int kc = 0; kc < 256; kc += 32) {
        bf16x8 af = *(const bf16x8*)(ctx + (long)arow * 256 + kc + g * 8);
#pragma unroll
        for (int nj = 0; nj < 4; nj++) {
            bf16x8 bf = *(const bf16x8*)(wout + (long)(h * 64 + nj * 16 + ln) * 256 + kc + g * 8);
            oa[nj] = __builtin_amdgcn_mfma_f32_16x16x32_bf16(af, bf, oa[nj], 0, 0, 0);
        }
    }
#pragma unroll
    for (int nj = 0; nj < 4; nj++) {
        int n = h * 64 + nj * 16 + ln;
        float bv = b_out[n];
#pragma unroll
        for (int r = 0; r < 4; r++) {
            int R = bm + g * 4 + r;
            if (R < M)
                pooled[(long)list[R] * 256 + n] = oa[nj][r] + bv;
        }
    }
}

// ---------------------------------------------------------------------------
// gemm_ln (round-13 known-good): company GEMM + residual + pooled + LN.
// ---------------------------------------------------------------------------
__global__ __launch_bounds__(256) void gemm_ln(
    const float* __restrict__ A, const unsigned short* __restrict__ W,
    const float* __restrict__ bias,
    const float* __restrict__ pooled, const float* __restrict__ csrc,
    const float* __restrict__ gamma, const float* __restrict__ beta,
    float* __restrict__ out, int M, int K)
{
    __shared__ unsigned short As[64 * 32];
    __shared__ unsigned short Ws[256 * 32];
    char* abase = (char*)As;
    char* wbase = (char*)Ws;

    const int bm = blockIdx.x * 64;
    const int t = threadIdx.x;
    const int wv = t >> 6, lane = t & 63, g = lane >> 4, ln = lane & 15;

    f32x4 acc[16];
#pragma unroll
    for (int i = 0; i < 16; i++) acc[i] = (f32x4){0.f, 0.f, 0.f, 0.f};

    const int sr = t >> 2;
    const int sc = (t & 3) * 8;
    int arow = bm + sr; if (arow > M - 1) arow = M - 1;
    const float* aptr = A + (long)arow * K + sc;

    for (int kc = 0; kc < K; kc += 32) {
        __syncthreads();
        stage_f32(aptr + kc, abase, sr, sc);
#pragma unroll
        for (int p = 0; p < 4; p++) {
            int r = p * 64 + sr;
            *(bf16x8*)(wbase + ((r * 64 + sc * 2) ^ SWZ(r))) =
                *(const bf16x8*)(W + (long)r * K + kc + sc);
        }
        __syncthreads();

        const int ar = wv * 16 + ln;
        bf16x8 af = *(bf16x8*)(abase + ((ar * 64 + g * 16) ^ SWZ(ar)));
#pragma unroll
        for (int nj = 0; nj < 16; nj++) {
            int wr = nj * 16 + ln;
            bf16x8 bf = *(bf16x8*)(wbase + ((wr * 64 + g * 16) ^ SWZ(wr)));
            acc[nj] = __builtin_amdgcn_mfma_f32_16x16x32_bf16(af, bf, acc[nj], 0, 0, 0);
        }
    }

#pragma unroll
    for (int r = 0; r < 4; r++) {
        int R = bm + wv * 16 + g * 4 + r;
        bool valid = R < M;
        int Rc = valid ? R : 0;
        float cntv = csrc[Rc];
        float factor = (valid && cntv > 0.f) ? cntv / (cntv + 1e-6f) : 0.f;

        float v[16];
        float sum = 0.f, sq = 0.f;
#pragma unroll
        for (int nj = 0; nj < 16; nj++) {
            int n = nj * 16 + ln;
            float x = acc[nj][r] + bias[n] + factor * pooled[(long)Rc * 256 + n];
            v[nj] = x;
            sum += x;
            sq  += x * x;
        }
#pragma unroll
        for (int st = 1; st < 16; st <<= 1) {
            sum += __shfl_xor(sum, st);
            sq  += __shfl_xor(sq,  st);
        }
        float mean = sum * (1.0f / 256.0f);
        float var  = sq * (1.0f / 256.0f) - mean * mean;
        float rstd = rsqrtf(var + 1e-5f);
        if (valid) {
#pragma unroll
            for (int nj = 0; nj < 16; nj++) {
                int n = nj * 16 + ln;
                out[(long)R * 256 + n] = (v[nj] - mean) * rstd * gamma[n] + beta[n];
            }
        }
    }
}

// ---------------------------------------------------------------------------
extern "C" void kernel_launch(void* const* d_in, const int* in_sizes, int n_in,
                              void* d_out, int out_size, void* d_ws, size_t ws_size,
                              hipStream_t stream)
{
    const float* company_x  = (const float*)d_in[0];
    const float* industry_x = (const float*)d_in[1];
    const int*   edge       = (const int*)d_in[2];
    const float* Wc         = (const float*)d_in[3];
    const float* bc         = (const float*)d_in[4];
    const float* Wi         = (const float*)d_in[5];
    const float* bi         = (const float*)d_in[6];
    const float* w_in       = (const float*)d_in[7];
    const float* b_in       = (const float*)d_in[8];
    const float* w_out      = (const float*)d_in[9];
    const float* b_out      = (const float*)d_in[10];
    const float* gamma      = (const float*)d_in[11];
    const float* beta       = (const float*)d_in[12];
    float* out = (float*)d_out;

    const int* src = edge;
    const int* tgt = edge + E_EDGES;

    // workspace carve (float units)
    float* wf = (float*)d_ws;
    size_t o = 0;
    unsigned short* Wc_bf   = (unsigned short*)(wf + o); o += 32768;  // 256x256
    unsigned short* wout_bf = (unsigned short*)(wf + o); o += 32768;
    unsigned short* WcT_bf  = (unsigned short*)(wf + o); o += 32768;
    unsigned short* Wi_bf   = (unsigned short*)(wf + o); o += 16384;  // 256x128
    unsigned short* wkv_bf  = (unsigned short*)(wf + o); o += 65536;  // 512x256
    unsigned short* Wcq_bf  = (unsigned short*)(wf + o); o += 32768;
    unsigned short* Kbuf    = (unsigned short*)(wf + o); o += 65536;  // 512x256
    unsigned short* VTg     = (unsigned short*)(wf + o); o += 65536;  // 256x512
    unsigned short* Qb      = (unsigned short*)(wf + o); o += (size_t)E_EDGES * 128;
    unsigned short* ctx     = (unsigned short*)(wf + o); o += (size_t)E_EDGES * 128;
    float* pooled           = wf + o; o += (size_t)N_COMP * 256;
    float* beff             = wf + o; o += 768;
    float* cntT             = wf + o; o += NKEYS;
    int*   list             = (int*)(wf + o); o += E_EDGES;
    // contiguous zeroed region: csrc | ctgt | nlist
    float* csrc             = wf + o; o += N_COMP;
    float* ctgt             = wf + o; o += NKEYS;
    int*   nlist            = (int*)(wf + o); o += 4;

    hipMemsetAsync(csrc, 0, (N_COMP + NKEYS + 4) * sizeof(float), stream);

    prep<<<dim3(220), dim3(256), 0, stream>>>(
        src, tgt, Wc, Wi, w_out, w_in, bc, bi, b_in,
        csrc, ctgt, Wc_bf, wout_bf, WcT_bf, Wi_bf, wkv_bf, beff);

    fusedW<<<dim3(99), dim3(256), 0, stream>>>(
        w_in, WcT_bf, industry_x, Wi_bf, wkv_bf, beff, ctgt, csrc,
        Wcq_bf, Kbuf, VTg, cntT, list, nlist);

    qproj<<<dim3(128), dim3(256), 0, stream>>>(
        company_x, list, nlist, Wcq_bf, beff, Qb);

    megattn<<<dim3(512), dim3(256), 0, stream>>>(
        Qb, Kbuf, VTg, cntT, nlist, ctx);

    out_proj<<<dim3(512), dim3(256), 0, stream>>>(
        ctx, wout_bf, b_out, list, nlist, pooled);

    gemm_ln<<<dim3((N_COMP + 63) / 64), dim3(256), 0, stream>>>(
        company_x, Wc_bf, bc, pooled, csrc, gamma, beta, out, N_COMP, 256);
}

// Round 20
// 106.326 us; speedup vs baseline: 1.1461x; 1.1461x over previous
//
#include <hip/hip_runtime.h>

#define E_EDGES 8192
#define N_COMP  20000
#define N_IND   500
#define NKEYS   512

typedef short bf16x8 __attribute__((ext_vector_type(8)));
typedef float f32x4  __attribute__((ext_vector_type(4)));

static __device__ __forceinline__ unsigned short f2bf(float v) {
    unsigned u = __builtin_bit_cast(unsigned, v);
    u = (u + 0x7FFFu + ((u >> 16) & 1u)) >> 16;
    return (unsigned short)u;
}

static __device__ __forceinline__ void cvt8(const float* __restrict__ s,
                                            unsigned short* __restrict__ d) {
    float4 a = *(const float4*)s;
    float4 b = *(const float4*)(s + 4);
    bf16x8 o;
    o[0] = (short)f2bf(a.x); o[1] = (short)f2bf(a.y);
    o[2] = (short)f2bf(a.z); o[3] = (short)f2bf(a.w);
    o[4] = (short)f2bf(b.x); o[5] = (short)f2bf(b.y);
    o[6] = (short)f2bf(b.z); o[7] = (short)f2bf(b.w);
    *(bf16x8*)d = o;
}

static __device__ __forceinline__ bf16x8 cvt8r(const float* __restrict__ s) {
    float4 a = *(const float4*)s;
    float4 b = *(const float4*)(s + 4);
    bf16x8 v;
    v[0] = (short)f2bf(a.x); v[1] = (short)f2bf(a.y);
    v[2] = (short)f2bf(a.z); v[3] = (short)f2bf(a.w);
    v[4] = (short)f2bf(b.x); v[5] = (short)f2bf(b.y);
    v[6] = (short)f2bf(b.z); v[7] = (short)f2bf(b.w);
    return v;
}

#define SWZ(r)   (((r) & 7) << 4)
#define SWZ4(r)  ((((r) >> 1) & 3) << 4)

static __device__ __forceinline__ void stage_f32(const float* src, char* base,
                                                 int sr, int sc) {
    *(bf16x8*)(base + ((sr * 64 + sc * 2) ^ SWZ(sr))) = cvt8r(src);
}

// zero-region layout (dwords): csrc[20000] | ctgt[512] | nlist[4] | flags[20000]
#define ZR_DWORDS (20000 + 512 + 4 + 20000)
#define ZR_VEC4   ((ZR_DWORDS + 3) / 4)   // 10129

// ---------------------------------------------------------------------------
// kernelA: everything with no data dependencies, block-range dispatched.
//  [0,40)    zero csrc/ctgt/nlist/flags (float4 stores)
//  [40,72)   Wc  -> bf16
//  [72,104)  w_out -> bf16
//  [104,108) beff[0:256] = w_in[e]·bc + b_in[e]
//  [108,112) Wcq = w_in[0:256] @ Wc   (B = Wc^T staged inline, strided)
//  [112,128) KV: ih = bf16(ix@Wi^T) (Wi staged raw); colh=0 -> Kbuf rows
//            (wk staged raw, bias inline); colh=1 -> VTg cols (swapped MFMA)
// ---------------------------------------------------------------------------
__global__ __launch_bounds__(256) void kernelA(
    const float* __restrict__ industry_x,
    const float* __restrict__ Wc, const float* __restrict__ Wi,
    const float* __restrict__ w_out, const float* __restrict__ w_in,
    const float* __restrict__ bc, const float* __restrict__ bi,
    const float* __restrict__ b_in,
    float* __restrict__ zregion,
    unsigned short* __restrict__ Wc_bf, unsigned short* __restrict__ wout_bf,
    unsigned short* __restrict__ Wcq_bf, unsigned short* __restrict__ Kbuf,
    unsigned short* __restrict__ VTg, float* __restrict__ beff)
{
    __shared__ char lds[50176];          // 48K GEMM scratch + 1K bias + pad
    float* biasb = (float*)(lds + 49152);

    const int bid = blockIdx.x, t = threadIdx.x;
    const int wv = t >> 6, lane = t & 63;
    const int g = lane >> 4, ln = lane & 15;
    const int sr = t >> 2, sc = (t & 3) * 8;

    if (bid < 40) {
        int idx = bid * 256 + t;
        if (idx < ZR_VEC4) {
            float4 z = {0.f, 0.f, 0.f, 0.f};
            *(float4*)(zregion + idx * 4) = z;
        }
        return;
    }
    if (bid < 72) {
        long i = ((long)(bid - 40) * 256 + t) * 8;
        cvt8(Wc + i, Wc_bf + i);
        return;
    }
    if (bid < 104) {
        long i = ((long)(bid - 72) * 256 + t) * 8;
        cvt8(w_out + i, wout_bf + i);
        return;
    }
    if (bid < 108) {
        int gi = (bid - 104) * 256 + t;      // [0,1024)
        int e = gi >> 2, q = gi & 3;         // e in [0,256)
        const float* wr = w_in + (long)e * 256 + q * 64;
        const float* br = bc + q * 64;
        float s = 0.f;
#pragma unroll
        for (int j = 0; j < 64; j += 4) {
            float4 w4 = *(const float4*)(wr + j);
            float4 b4 = *(const float4*)(br + j);
            s += w4.x * b4.x + w4.y * b4.y + w4.z * b4.z + w4.w * b4.w;
        }
        s += __shfl_xor(s, 1);
        s += __shfl_xor(s, 2);
        if (q == 0) beff[e] = s + b_in[e];
        return;
    }

    if (bid < 112) {
        // ---- Wcq = w_in[0:256] @ Wc (contract over Wc row index) ----
        char* ab = lds;            // 4 KB
        char* wb = lds + 4 * 1024; // 16 KB
        const int bm = (bid - 108) * 64;
        f32x4 acc[16];
#pragma unroll
        for (int i = 0; i < 16; i++) acc[i] = (f32x4){0.f, 0.f, 0.f, 0.f};
        const float* aptr = w_in + (long)(bm + sr) * 256 + sc;
        for (int kc = 0; kc < 256; kc += 32) {
            __syncthreads();
            stage_f32(aptr + kc, ab, sr, sc);
#pragma unroll
            for (int p = 0; p < 4; p++) {
                int r = p * 64 + sr;
                bf16x8 v;
#pragma unroll
                for (int j = 0; j < 8; j++)
                    v[j] = (short)f2bf(Wc[(long)(kc + sc + j) * 256 + r]);
                *(bf16x8*)(wb + ((r * 64 + sc * 2) ^ SWZ(r))) = v;
            }
            __syncthreads();
            int ar = wv * 16 + ln;
            bf16x8 af = *(bf16x8*)(ab + ((ar * 64 + g * 16) ^ SWZ(ar)));
#pragma unroll
            for (int nj = 0; nj < 16; nj++) {
                int wr = nj * 16 + ln;
                bf16x8 bf = *(bf16x8*)(wb + ((wr * 64 + g * 16) ^ SWZ(wr)));
                acc[nj] = __builtin_amdgcn_mfma_f32_16x16x32_bf16(af, bf, acc[nj], 0, 0, 0);
            }
        }
#pragma unroll
        for (int nj = 0; nj < 16; nj++)
#pragma unroll
            for (int r = 0; r < 4; r++)
                Wcq_bf[(long)(bm + wv * 16 + g * 4 + r) * 256 + nj * 16 + ln] =
                    f2bf(acc[nj][r]);
        return;
    }

    // ---- KV blocks ----
    const int rg = (bid - 112) >> 1, colh = (bid - 112) & 1;
    char* ab  = lds;             // 4 KB  (phase-1 A)
    char* wb1 = lds + 4 * 1024;  // 16 KB (phase-1 W)
    char* ihb = lds + 16 * 1024; // 32 KB (ih [64][256] bf16, rows 512B)
    char* wb2 = lds;             // 16 KB (phase-2 W)

    // bias slice for this half: beff-equivalent = w_in[e]·bi + b_in[e],
    // e = 256 + colh*256 + t  (full 256-length dot)
    {
        int e = 256 + colh * 256 + t;
        const float* wr = w_in + (long)e * 256;
        float s = 0.f;
#pragma unroll
        for (int j = 0; j < 256; j += 4) {
            float4 w4 = *(const float4*)(wr + j);
            float4 b4 = *(const float4*)(bi + j);
            s += w4.x * b4.x + w4.y * b4.y + w4.z * b4.z + w4.w * b4.w;
        }
        biasb[t] = s + b_in[e];
    }

    // phase 1: ih = industry_x @ Wi^T  (64 rows x 256, K=128; Wi staged raw)
    {
        f32x4 a1[16];
#pragma unroll
        for (int i = 0; i < 16; i++) a1[i] = (f32x4){0.f, 0.f, 0.f, 0.f};
        int arow = rg * 64 + sr; if (arow > N_IND - 1) arow = N_IND - 1;
        const float* aptr = industry_x + (long)arow * 128 + sc;
        for (int kc = 0; kc < 128; kc += 32) {
            __syncthreads();
            stage_f32(aptr + kc, ab, sr, sc);
#pragma unroll
            for (int p = 0; p < 4; p++) {
                int r = p * 64 + sr;
                *(bf16x8*)(wb1 + ((r * 64 + sc * 2) ^ SWZ(r))) =
                    cvt8r(Wi + (long)r * 128 + kc + sc);
            }
            __syncthreads();
            int ar = wv * 16 + ln;
            bf16x8 af = *(bf16x8*)(ab + ((ar * 64 + g * 16) ^ SWZ(ar)));
#pragma unroll
            for (int nj = 0; nj < 16; nj++) {
                int wr = nj * 16 + ln;
                bf16x8 bf = *(bf16x8*)(wb1 + ((wr * 64 + g * 16) ^ SWZ(wr)));
                a1[nj] = __builtin_amdgcn_mfma_f32_16x16x32_bf16(af, bf, a1[nj], 0, 0, 0);
            }
        }
        __syncthreads();
#pragma unroll
        for (int nj = 0; nj < 16; nj++)
#pragma unroll
            for (int r = 0; r < 4; r++) {
                int row = wv * 16 + g * 4 + r, col = nj * 16 + ln;
                *(unsigned short*)(ihb + ((row * 512 + col * 2) ^ SWZ(row))) =
                    f2bf(a1[nj][r]);
            }
    }
    __syncthreads();

    const float* wraw = w_in + (long)(256 + colh * 256) * 256;  // wk or wv rows

    if (colh == 0) {
        f32x4 a2[16];
#pragma unroll
        for (int i = 0; i < 16; i++) a2[i] = (f32x4){0.f, 0.f, 0.f, 0.f};
        for (int kc = 0; kc < 256; kc += 32) {
            __syncthreads();
#pragma unroll
            for (int p = 0; p < 4; p++) {
                int r = p * 64 + sr;
                *(bf16x8*)(wb2 + ((r * 64 + sc * 2) ^ SWZ(r))) =
                    cvt8r(wraw + (long)r * 256 + kc + sc);
            }
            __syncthreads();
            int row = wv * 16 + ln;
            bf16x8 af = *(bf16x8*)(ihb + ((row * 512 + (kc + g * 8) * 2) ^ SWZ(row)));
#pragma unroll
            for (int nj = 0; nj < 16; nj++) {
                int wr = nj * 16 + ln;
                bf16x8 bf = *(bf16x8*)(wb2 + ((wr * 64 + g * 16) ^ SWZ(wr)));
                a2[nj] = __builtin_amdgcn_mfma_f32_16x16x32_bf16(af, bf, a2[nj], 0, 0, 0);
            }
        }
#pragma unroll
        for (int nj = 0; nj < 16; nj++)
#pragma unroll
            for (int r = 0; r < 4; r++) {
                int R = rg * 64 + wv * 16 + g * 4 + r, n = nj * 16 + ln;
                Kbuf[(long)R * 256 + n] = f2bf(a2[nj][r] + biasb[n]);
            }
    } else {
        f32x4 a2[16];
#pragma unroll
        for (int i = 0; i < 16; i++) a2[i] = (f32x4){0.f, 0.f, 0.f, 0.f};
        for (int kc = 0; kc < 256; kc += 32) {
            __syncthreads();
#pragma unroll
            for (int p = 0; p < 4; p++) {
                int r = p * 64 + sr;
                *(bf16x8*)(wb2 + ((r * 64 + sc * 2) ^ SWZ(r))) =
                    cvt8r(wraw + (long)r * 256 + kc + sc);
            }
            __syncthreads();
#pragma unroll
            for (int mi = 0; mi < 4; mi++) {
                int arow = wv * 64 + mi * 16 + ln;
                bf16x8 af = *(bf16x8*)(wb2 + ((arow * 64 + g * 16) ^ SWZ(arow)));
#pragma unroll
                for (int t4 = 0; t4 < 4; t4++) {
                    int brow = t4 * 16 + ln;
                    bf16x8 bfr = *(bf16x8*)(ihb + ((brow * 512 + (kc + g * 8) * 2) ^ SWZ(brow)));
                    a2[mi * 4 + t4] = __builtin_amdgcn_mfma_f32_16x16x32_bf16(af, bfr, a2[mi * 4 + t4], 0, 0, 0);
                }
            }
        }
#pragma unroll
        for (int mi = 0; mi < 4; mi++)
#pragma unroll
            for (int t4 = 0; t4 < 4; t4++)
#pragma unroll
                for (int r = 0; r < 4; r++) {
                    int nrow = wv * 64 + mi * 16 + g * 4 + r;
                    VTg[(long)nrow * 512 + rg * 64 + t4 * 16 + ln] =
                        f2bf(a2[mi * 4 + t4][r] + biasb[nrow]);
                }
    }
}

// ---------------------------------------------------------------------------
// kernelB: edge counting + distinct-src compaction in one pass (CAS claim).
// ---------------------------------------------------------------------------
__global__ __launch_bounds__(256) void kernelB(
    const int* __restrict__ src, const int* __restrict__ tgt,
    float* __restrict__ csrc, float* __restrict__ ctgt,
    int* __restrict__ flags, int* __restrict__ nlist, int* __restrict__ list)
{
    int e = blockIdx.x * 256 + threadIdx.x;
    int s = src[e];
    atomicAdd(&csrc[s], 1.0f);
    atomicAdd(&ctgt[tgt[e]], 1.0f);
    if (atomicCAS(&flags[s], 0, 1) == 0) {
        int k = atomicAdd(nlist, 1);
        list[k] = s;
    }
}

// ---------------------------------------------------------------------------
// megattn (round-13 v8, measured 54-56 us): 16 listed rows/block, wave=head.
// stage x -> Q proj -> flash attention (2 tiles x 256 keys, grouped K loads,
// VT prefetch) -> out-proj -> pooled[list[R]]. cnt read straight from ctgt.
// ---------------------------------------------------------------------------
__global__ __launch_bounds__(256, 2) void megattn(
    const float* __restrict__ company_x,
    const unsigned short* __restrict__ Wcq,
    const float* __restrict__ beff,
    const unsigned short* __restrict__ Kbuf,
    const unsigned short* __restrict__ VTg,
    const float* __restrict__ ctgt,
    const unsigned short* __restrict__ wout,
    const float* __restrict__ b_out,
    const int* __restrict__ list, const int* __restrict__ nlist,
    float* __restrict__ pooled)
{
    const int M = *nlist;
    const int bm = blockIdx.x * 16;
    if (bm >= M) return;

    __shared__ char lds[32768];
    const int t = threadIdx.x, h = t >> 6, lane = t & 63;
    const int g = lane >> 4, ln = lane & 15;
    char* qbase = lds + h * 2048;            // per-wave ctx/q [16][64] bf16
    char* xbase = lds + 8192;                // [16][256] bf16 (Q phase only)
    char* pbase = lds + 16384 + h * 4096;    // per-wave P 4-slot buffer

    // ---- 1. stage x ----
    {
        int row = t >> 4, c0 = (t & 15) * 16;
        int mr = bm + row; if (mr > M - 1) mr = M - 1;
        const float* src = company_x + (long)list[mr] * 256 + c0;
        *(bf16x8*)(xbase + ((row * 512 + c0 * 2) ^ SWZ(row))) = cvt8r(src);
        *(bf16x8*)(xbase + ((row * 512 + c0 * 2 + 16) ^ SWZ(row))) = cvt8r(src + 8);
    }
    __syncthreads();

    // ---- 2. Q (per wave) ----
    bf16x8 qf0, qf1;
    {
        f32x4 qa[4];
#pragma unroll
        for (int i = 0; i < 4; i++) qa[i] = (f32x4){0.f, 0.f, 0.f, 0.f};
#pragma unroll
        for (int kc = 0; kc < 256; kc += 32) {
            bf16x8 af = *(bf16x8*)(xbase + ((ln * 512 + (kc + g * 8) * 2) ^ SWZ(ln)));
#pragma unroll
            for (int nj = 0; nj < 4; nj++) {
                bf16x8 bf = *(const bf16x8*)(Wcq + (long)(h * 64 + nj * 16 + ln) * 256 + kc + g * 8);
                qa[nj] = __builtin_amdgcn_mfma_f32_16x16x32_bf16(af, bf, qa[nj], 0, 0, 0);
            }
        }
#pragma unroll
        for (int nj = 0; nj < 4; nj++)
#pragma unroll
            for (int r = 0; r < 4; r++) {
                int row = g * 4 + r, col = nj * 16 + ln;
                *(unsigned short*)(qbase + ((row * 128 + col * 2) ^ SWZ(row))) =
                    f2bf((qa[nj][r] + beff[h * 64 + col]) * 0.125f);
            }
        qf0 = *(bf16x8*)(qbase + ((ln * 128 + g * 16) ^ SWZ(ln)));
        qf1 = *(bf16x8*)(qbase + ((ln * 128 + 64 + g * 16) ^ SWZ(ln)));
    }

    // ---- 3. flash attention, 2 tiles x 256 keys ----
    f32x4 acc[4];
#pragma unroll
    for (int i = 0; i < 4; i++) acc[i] = (f32x4){0.f, 0.f, 0.f, 0.f};
    float mreg[4] = {-1e30f, -1e30f, -1e30f, -1e30f};
    float lreg[4] = {0.f, 0.f, 0.f, 0.f};

#pragma unroll
    for (int tile = 0; tile < 2; tile++) {
        // counts: key = tile*256 + c*32 + sub*16 + ln
        float cnt[16];
#pragma unroll
        for (int j = 0; j < 16; j++)
            cnt[j] = ctgt[tile * 256 + (j >> 1) * 32 + (j & 1) * 16 + ln];

        // QK^T: 2 halves, each = 16 grouped loads then 16 MFMA pairs
        f32x4 S[8][2];
#pragma unroll
        for (int half = 0; half < 2; half++) {
            bf16x8 k0r[4][2], k1r[4][2];
#pragma unroll
            for (int c4 = 0; c4 < 4; c4++)
#pragma unroll
                for (int sub = 0; sub < 2; sub++) {
                    const unsigned short* kr = Kbuf +
                        (long)(tile * 256 + (half * 4 + c4) * 32 + sub * 16 + ln) * 256 + h * 64 + g * 8;
                    k0r[c4][sub] = *(const bf16x8*)(kr);
                    k1r[c4][sub] = *(const bf16x8*)(kr + 32);
                }
#pragma unroll
            for (int c4 = 0; c4 < 4; c4++)
#pragma unroll
                for (int sub = 0; sub < 2; sub++) {
                    f32x4 s = (f32x4){0.f, 0.f, 0.f, 0.f};
                    s = __builtin_amdgcn_mfma_f32_16x16x32_bf16(qf0, k0r[c4][sub], s, 0, 0, 0);
                    s = __builtin_amdgcn_mfma_f32_16x16x32_bf16(qf1, k1r[c4][sub], s, 0, 0, 0);
                    S[half * 4 + c4][sub] = s;
                }
        }

        // prefetch VT for chunks 0-1 before softmax
        bf16x8 vr[2][2][4];
#pragma unroll
        for (int j = 0; j < 2; j++)
#pragma unroll
            for (int t4 = 0; t4 < 4; t4++)
                vr[0][j][t4] = *(const bf16x8*)(
                    VTg + (long)(h * 64 + t4 * 16 + ln) * 512 + tile * 256 + j * 32 + g * 8);

        float tm[4] = {-1e30f, -1e30f, -1e30f, -1e30f};
#pragma unroll
        for (int c = 0; c < 8; c++)
#pragma unroll
            for (int sub = 0; sub < 2; sub++)
#pragma unroll
                for (int r = 0; r < 4; r++) tm[r] = fmaxf(tm[r], S[c][sub][r]);
#pragma unroll
        for (int st = 1; st < 16; st <<= 1)
#pragma unroll
            for (int r = 0; r < 4; r++) tm[r] = fmaxf(tm[r], __shfl_xor(tm[r], st));

        float corr[4];
#pragma unroll
        for (int r = 0; r < 4; r++) {
            float mn = fmaxf(mreg[r], tm[r]);
            corr[r] = __expf(mreg[r] - mn);
            mreg[r] = mn;
        }

        float ps[4] = {0.f, 0.f, 0.f, 0.f};
#pragma unroll
        for (int c = 0; c < 8; c++)
#pragma unroll
            for (int sub = 0; sub < 2; sub++) {
                float cv = cnt[c * 2 + sub];
#pragma unroll
                for (int r = 0; r < 4; r++) {
                    float p = cv * __expf(S[c][sub][r] - mreg[r]);
                    S[c][sub][r] = p;
                    ps[r] += p;
                }
            }
#pragma unroll
        for (int st = 1; st < 16; st <<= 1)
#pragma unroll
            for (int r = 0; r < 4; r++) ps[r] += __shfl_xor(ps[r], st);
#pragma unroll
        for (int r = 0; r < 4; r++) lreg[r] = lreg[r] * corr[r] + ps[r];
#pragma unroll
        for (int i = 0; i < 4; i++)
#pragma unroll
            for (int r = 0; r < 4; r++) acc[i][r] *= corr[r];

        // PV: 4 groups of 2 chunks; prefetch grp+1 while computing grp
#pragma unroll
        for (int grp = 0; grp < 4; grp++) {
            if (grp < 3) {
#pragma unroll
                for (int j = 0; j < 2; j++)
#pragma unroll
                    for (int t4 = 0; t4 < 4; t4++)
                        vr[(grp + 1) & 1][j][t4] = *(const bf16x8*)(
                            VTg + (long)(h * 64 + t4 * 16 + ln) * 512 +
                            tile * 256 + ((grp + 1) * 2 + j) * 32 + g * 8);
            }
#pragma unroll
            for (int j = 0; j < 2; j++) {
                int c = grp * 2 + j;
                char* pb = pbase + (c & 3) * 1024;
#pragma unroll
                for (int sub = 0; sub < 2; sub++)
#pragma unroll
                    for (int r = 0; r < 4; r++) {
                        int row = g * 4 + r;
                        *(unsigned short*)(pb + ((row * 64 + (sub * 16 + ln) * 2) ^ SWZ4(row))) =
                            f2bf(S[c][sub][r]);
                    }
                bf16x8 pa = *(bf16x8*)(pb + ((ln * 64 + g * 16) ^ SWZ4(ln)));
#pragma unroll
                for (int t4 = 0; t4 < 4; t4++)
                    acc[t4] = __builtin_amdgcn_mfma_f32_16x16x32_bf16(
                        pa, vr[grp & 1][j][t4], acc[t4], 0, 0, 0);
            }
        }
    }

    // ---- 4. ctx_h -> own q slot ----
#pragma unroll
    for (int t4 = 0; t4 < 4; t4++)
#pragma unroll
        for (int r = 0; r < 4; r++) {
            int row = g * 4 + r, col = t4 * 16 + ln;
            *(unsigned short*)(qbase + ((row * 128 + col * 2) ^ SWZ(row))) =
                f2bf(acc[t4][r] / lreg[r]);
        }
    __syncthreads();

    // ---- 5. out-proj cols [64h, 64h+64) -> pooled ----
    {
        f32x4 oa[4];
#pragma unroll
        for (int i = 0; i < 4; i++) oa[i] = (f32x4){0.f, 0.f, 0.f, 0.f};
#pragma unroll
        for (int kc = 0; kc < 256; kc += 32) {
            int hs = kc >> 6;
            int off = (kc & 63) + g * 8;
            bf16x8 af = *(bf16x8*)(lds + hs * 2048 + ((ln * 128 + off * 2) ^ SWZ(ln)));
#pragma unroll
            for (int nj = 0; nj < 4; nj++) {
                bf16x8 bf = *(const bf16x8*)(wout + (long)(h * 64 + nj * 16 + ln) * 256 + kc + g * 8);
                oa[nj] = __builtin_amdgcn_mfma_f32_16x16x32_bf16(af, bf, oa[nj], 0, 0, 0);
            }
        }
#pragma unroll
        for (int nj = 0; nj < 4; nj++) {
            int n = h * 64 + nj * 16 + ln;
            float bv = b_out[n];
#pragma unroll
            for (int r = 0; r < 4; r++) {
                int R = bm + g * 4 + r;
                if (R < M)
                    pooled[(long)list[R] * 256 + n] = oa[nj][r] + bv;
            }
        }
    }
}

// ---------------------------------------------------------------------------
// gemm_ln (round-13 known-good): company GEMM + residual + pooled + LN.
// ---------------------------------------------------------------------------
__global__ __launch_bounds__(256) void gemm_ln(
    const float* __restrict__ A, const unsigned short* __restrict__ W,
    const float* __restrict__ bias,
    const float* __restrict__ pooled, const float* __restrict__ csrc,
    const float* __restrict__ gamma, const float* __restrict__ beta,
    float* __restrict__ out, int M, int K)
{
    __shared__ unsigned short As[64 * 32];
    __shared__ unsigned short Ws[256 * 32];
    char* abase = (char*)As;
    char* wbase = (char*)Ws;

    const int bm = blockIdx.x * 64;
    const int t = threadIdx.x;
    const int wv = t >> 6, lane = t & 63, g = lane >> 4, ln = lane & 15;

    f32x4 acc[16];
#pragma unroll
    for (int i = 0; i < 16; i++) acc[i] = (f32x4){0.f, 0.f, 0.f, 0.f};

    const int sr = t >> 2;
    const int sc = (t & 3) * 8;
    int arow = bm + sr; if (arow > M - 1) arow = M - 1;
    const float* aptr = A + (long)arow * K + sc;

    for (int kc = 0; kc < K; kc += 32) {
        __syncthreads();
        stage_f32(aptr + kc, abase, sr, sc);
#pragma unroll
        for (int p = 0; p < 4; p++) {
            int r = p * 64 + sr;
            *(bf16x8*)(wbase + ((r * 64 + sc * 2) ^ SWZ(r))) =
                *(const bf16x8*)(W + (long)r * K + kc + sc);
        }
        __syncthreads();

        const int ar = wv * 16 + ln;
        bf16x8 af = *(bf16x8*)(abase + ((ar * 64 + g * 16) ^ SWZ(ar)));
#pragma unroll
        for (int nj = 0; nj < 16; nj++) {
            int wr = nj * 16 + ln;
            bf16x8 bf = *(bf16x8*)(wbase + ((wr * 64 + g * 16) ^ SWZ(wr)));
            acc[nj] = __builtin_amdgcn_mfma_f32_16x16x32_bf16(af, bf, acc[nj], 0, 0, 0);
        }
    }

#pragma unroll
    for (int r = 0; r < 4; r++) {
        int R = bm + wv * 16 + g * 4 + r;
        bool valid = R < M;
        int Rc = valid ? R : 0;
        float cntv = csrc[Rc];
        float factor = (valid && cntv > 0.f) ? cntv / (cntv + 1e-6f) : 0.f;

        float v[16];
        float sum = 0.f, sq = 0.f;
#pragma unroll
        for (int nj = 0; nj < 16; nj++) {
            int n = nj * 16 + ln;
            float x = acc[nj][r] + bias[n] + factor * pooled[(long)Rc * 256 + n];
            v[nj] = x;
            sum += x;
            sq  += x * x;
        }
#pragma unroll
        for (int st = 1; st < 16; st <<= 1) {
            sum += __shfl_xor(sum, st);
            sq  += __shfl_xor(sq,  st);
        }
        float mean = sum * (1.0f / 256.0f);
        float var  = sq * (1.0f / 256.0f) - mean * mean;
        float rstd = rsqrtf(var + 1e-5f);
        if (valid) {
#pragma unroll
            for (int nj = 0; nj < 16; nj++) {
                int n = nj * 16 + ln;
                out[(long)R * 256 + n] = (v[nj] - mean) * rstd * gamma[n] + beta[n];
            }
        }
    }
}

// ---------------------------------------------------------------------------
extern "C" void kernel_launch(void* const* d_in, const int* in_sizes, int n_in,
                              void* d_out, int out_size, void* d_ws, size_t ws_size,
                              hipStream_t stream)
{
    const float* company_x  = (const float*)d_in[0];
    const float* industry_x = (const float*)d_in[1];
    const int*   edge       = (const int*)d_in[2];
    const float* Wc         = (const float*)d_in[3];
    const float* bc         = (const float*)d_in[4];
    const float* Wi         = (const float*)d_in[5];
    const float* bi         = (const float*)d_in[6];
    const float* w_in       = (const float*)d_in[7];
    const float* b_in       = (const float*)d_in[8];
    const float* w_out      = (const float*)d_in[9];
    const float* b_out      = (const float*)d_in[10];
    const float* gamma      = (const float*)d_in[11];
    const float* beta       = (const float*)d_in[12];
    float* out = (float*)d_out;

    const int* src = edge;
    const int* tgt = edge + E_EDGES;

    // workspace carve (float units)
    float* wf = (float*)d_ws;
    size_t o = 0;
    unsigned short* Wc_bf   = (unsigned short*)(wf + o); o += 32768;  // 256x256
    unsigned short* wout_bf = (unsigned short*)(wf + o); o += 32768;
    unsigned short* Wcq_bf  = (unsigned short*)(wf + o); o += 32768;
    unsigned short* Kbuf    = (unsigned short*)(wf + o); o += 65536;  // 512x256
    unsigned short* VTg     = (unsigned short*)(wf + o); o += 65536;  // 256x512
    float* pooled           = wf + o; o += (size_t)N_COMP * 256;
    float* beff             = wf + o; o += 768;
    int*   list             = (int*)(wf + o); o += E_EDGES;
    // zero region: csrc | ctgt | nlist | flags (zeroed by kernelA)
    float* zregion          = wf + o;
    float* csrc             = wf + o; o += N_COMP;
    float* ctgt             = wf + o; o += NKEYS;
    int*   nlist            = (int*)(wf + o); o += 4;
    int*   flags            = (int*)(wf + o); o += N_COMP;

    kernelA<<<dim3(128), dim3(256), 0, stream>>>(
        industry_x, Wc, Wi, w_out, w_in, bc, bi, b_in,
        zregion, Wc_bf, wout_bf, Wcq_bf, Kbuf, VTg, beff);

    kernelB<<<dim3(E_EDGES / 256), dim3(256), 0, stream>>>(
        src, tgt, csrc, ctgt, flags, nlist, list);

    megattn<<<dim3(512), dim3(256), 0, stream>>>(
        company_x, Wcq_bf, beff, Kbuf, VTg, ctgt, wout_bf, b_out,
        list, nlist, pooled);

    gemm_ln<<<dim3((N_COMP + 63) / 64), dim3(256), 0, stream>>>(
        company_x, Wc_bf, bc, pooled, csrc, gamma, beta, out, N_COMP, 256);
}

// Round 21
// 95.917 us; speedup vs baseline: 1.2704x; 1.1085x over previous
//
#include <hip/hip_runtime.h>

#define E_EDGES 8192
#define N_COMP  20000
#define N_IND   500
#define NKEYS   512

typedef short bf16x8 __attribute__((ext_vector_type(8)));
typedef float f32x4  __attribute__((ext_vector_type(4)));

static __device__ __forceinline__ unsigned short f2bf(float v) {
    unsigned u = __builtin_bit_cast(unsigned, v);
    u = (u + 0x7FFFu + ((u >> 16) & 1u)) >> 16;
    return (unsigned short)u;
}

static __device__ __forceinline__ void cvt8(const float* __restrict__ s,
                                            unsigned short* __restrict__ d) {
    float4 a = *(const float4*)s;
    float4 b = *(const float4*)(s + 4);
    bf16x8 o;
    o[0] = (short)f2bf(a.x); o[1] = (short)f2bf(a.y);
    o[2] = (short)f2bf(a.z); o[3] = (short)f2bf(a.w);
    o[4] = (short)f2bf(b.x); o[5] = (short)f2bf(b.y);
    o[6] = (short)f2bf(b.z); o[7] = (short)f2bf(b.w);
    *(bf16x8*)d = o;
}

static __device__ __forceinline__ bf16x8 cvt8r(const float* __restrict__ s) {
    float4 a = *(const float4*)s;
    float4 b = *(const float4*)(s + 4);
    bf16x8 v;
    v[0] = (short)f2bf(a.x); v[1] = (short)f2bf(a.y);
    v[2] = (short)f2bf(a.z); v[3] = (short)f2bf(a.w);
    v[4] = (short)f2bf(b.x); v[5] = (short)f2bf(b.y);
    v[6] = (short)f2bf(b.z); v[7] = (short)f2bf(b.w);
    return v;
}

#define SWZ(r)   (((r) & 7) << 4)
#define SWZ4(r)  ((((r) >> 1) & 3) << 4)

static __device__ __forceinline__ void stage_f32(const float* src, char* base,
                                                 int sr, int sc) {
    *(bf16x8*)(base + ((sr * 64 + sc * 2) ^ SWZ(sr))) = cvt8r(src);
}

// zero-region layout (dwords): csrc[20000] | ctgt[512] | nlist[4] | flags[20000]
#define ZR_DWORDS (20000 + 512 + 4 + 20000)
#define ZR_VEC4   ((ZR_DWORDS + 3) / 4)   // 10129

// ---------------------------------------------------------------------------
// prepZ: all independent preprocessing, block-range dispatched.
//  [0,40)    zero csrc/ctgt/nlist/flags
//  [40,72)   Wc -> bf16          [72,104)  w_out -> bf16
//  [104,136) Wc^T -> bf16        [136,152) Wi -> bf16
//  [152,216) w_kv -> bf16        [216,228) beff
// ---------------------------------------------------------------------------
__global__ __launch_bounds__(256) void prepZ(
    const float* __restrict__ Wc, const float* __restrict__ Wi,
    const float* __restrict__ w_out, const float* __restrict__ w_in,
    const float* __restrict__ bc, const float* __restrict__ bi,
    const float* __restrict__ b_in,
    float* __restrict__ zregion,
    unsigned short* __restrict__ Wc_bf, unsigned short* __restrict__ wout_bf,
    unsigned short* __restrict__ WcT_bf, unsigned short* __restrict__ Wi_bf,
    unsigned short* __restrict__ wkv_bf, float* __restrict__ beff)
{
    const int bid = blockIdx.x, tid = threadIdx.x;
    if (bid < 40) {
        int idx = bid * 256 + tid;
        if (idx < ZR_VEC4) {
            float4 z = {0.f, 0.f, 0.f, 0.f};
            *(float4*)(zregion + idx * 4) = z;
        }
    } else if (bid < 72) {
        long i = ((long)(bid - 40) * 256 + tid) * 8;
        cvt8(Wc + i, Wc_bf + i);
    } else if (bid < 104) {
        long i = ((long)(bid - 72) * 256 + tid) * 8;
        cvt8(w_out + i, wout_bf + i);
    } else if (bid < 136) {
        long o = ((long)(bid - 104) * 256 + tid) * 8;
        int c = (int)(o >> 8), d0 = (int)(o & 255);
        bf16x8 v;
#pragma unroll
        for (int j = 0; j < 8; j++) v[j] = (short)f2bf(Wc[(long)(d0 + j) * 256 + c]);
        *(bf16x8*)(WcT_bf + o) = v;
    } else if (bid < 152) {
        long i = ((long)(bid - 136) * 256 + tid) * 8;
        cvt8(Wi + i, Wi_bf + i);
    } else if (bid < 216) {
        long i = ((long)(bid - 152) * 256 + tid) * 8;
        cvt8(w_in + 65536 + i, wkv_bf + i);
    } else {
        int gi = (bid - 216) * 256 + tid;      // [0, 3072)
        int e = gi >> 2, q = gi & 3;
        const float* base = (e < 256) ? bc : bi;
        const float* wr = w_in + (long)e * 256 + q * 64;
        const float* br = base + q * 64;
        float s = 0.f;
#pragma unroll
        for (int j = 0; j < 64; j += 4) {
            float4 w4 = *(const float4*)(wr + j);
            float4 b4 = *(const float4*)(br + j);
            s += w4.x * b4.x + w4.y * b4.y + w4.z * b4.z + w4.w * b4.w;
        }
        s += __shfl_xor(s, 1);
        s += __shfl_xor(s, 2);
        if (q == 0) beff[e] = s + b_in[e];
    }
}

// ---------------------------------------------------------------------------
// fusedWB: block-range dispatch.
//  [0,4)   Wcq = w_in[0:256] @ WcT^T  (LDS-staged, r13 verbatim)
//  [4,20)  KV: ih = bf16(ix@Wi^T); colh=0 -> Kbuf; colh=1 -> VTg (swapped)
//  [20,52) edge counting + CAS-claim distinct-src compaction
// ---------------------------------------------------------------------------
__global__ __launch_bounds__(256) void fusedWB(
    const float* __restrict__ w_in, const unsigned short* __restrict__ WcT_bf,
    const float* __restrict__ industry_x, const unsigned short* __restrict__ Wi_bf,
    const unsigned short* __restrict__ wkv_bf, const float* __restrict__ beff,
    const int* __restrict__ src, const int* __restrict__ tgt,
    float* __restrict__ csrc, float* __restrict__ ctgt,
    int* __restrict__ flags, int* __restrict__ nlist, int* __restrict__ list,
    unsigned short* __restrict__ Wcq_bf, unsigned short* __restrict__ Kbuf,
    unsigned short* __restrict__ VTg)
{
    const int bid = blockIdx.x;
    if (bid >= 20) {
        int e = (bid - 20) * 256 + threadIdx.x;
        int s = src[e];
        atomicAdd(&csrc[s], 1.0f);
        atomicAdd(&ctgt[tgt[e]], 1.0f);
        if (atomicCAS(&flags[s], 0, 1) == 0) {
            int k = atomicAdd(nlist, 1);
            list[k] = s;
        }
        return;
    }

    __shared__ char lds[48 * 1024];
    const int t = threadIdx.x, wv = t >> 6, lane = t & 63;
    const int g = lane >> 4, ln = lane & 15;
    const int sr = t >> 2, sc = (t & 3) * 8;

    if (bid < 4) {
        char* ab = lds;
        char* wb = lds + 4 * 1024;
        const int bm = bid * 64;
        f32x4 acc[16];
#pragma unroll
        for (int i = 0; i < 16; i++) acc[i] = (f32x4){0.f, 0.f, 0.f, 0.f};
        const float* aptr = w_in + (long)(bm + sr) * 256 + sc;
        for (int kc = 0; kc < 256; kc += 32) {
            __syncthreads();
            stage_f32(aptr + kc, ab, sr, sc);
#pragma unroll
            for (int p = 0; p < 4; p++) {
                int r = p * 64 + sr;
                *(bf16x8*)(wb + ((r * 64 + sc * 2) ^ SWZ(r))) =
                    *(const bf16x8*)(WcT_bf + (long)r * 256 + kc + sc);
            }
            __syncthreads();
            int ar = wv * 16 + ln;
            bf16x8 af = *(bf16x8*)(ab + ((ar * 64 + g * 16) ^ SWZ(ar)));
#pragma unroll
            for (int nj = 0; nj < 16; nj++) {
                int wr = nj * 16 + ln;
                bf16x8 bf = *(bf16x8*)(wb + ((wr * 64 + g * 16) ^ SWZ(wr)));
                acc[nj] = __builtin_amdgcn_mfma_f32_16x16x32_bf16(af, bf, acc[nj], 0, 0, 0);
            }
        }
#pragma unroll
        for (int nj = 0; nj < 16; nj++)
#pragma unroll
            for (int r = 0; r < 4; r++)
                Wcq_bf[(long)(bm + wv * 16 + g * 4 + r) * 256 + nj * 16 + ln] =
                    f2bf(acc[nj][r]);
        return;
    }

    const int rg = (bid - 4) >> 1, colh = (bid - 4) & 1;
    char* ab  = lds;
    char* wb1 = lds + 4 * 1024;
    char* ihb = lds + 16 * 1024;
    char* wb2 = lds;

    {
        f32x4 a1[16];
#pragma unroll
        for (int i = 0; i < 16; i++) a1[i] = (f32x4){0.f, 0.f, 0.f, 0.f};
        int arow = rg * 64 + sr; if (arow > N_IND - 1) arow = N_IND - 1;
        const float* aptr = industry_x + (long)arow * 128 + sc;
        for (int kc = 0; kc < 128; kc += 32) {
            __syncthreads();
            stage_f32(aptr + kc, ab, sr, sc);
#pragma unroll
            for (int p = 0; p < 4; p++) {
                int r = p * 64 + sr;
                *(bf16x8*)(wb1 + ((r * 64 + sc * 2) ^ SWZ(r))) =
                    *(const bf16x8*)(Wi_bf + (long)r * 128 + kc + sc);
            }
            __syncthreads();
            int ar = wv * 16 + ln;
            bf16x8 af = *(bf16x8*)(ab + ((ar * 64 + g * 16) ^ SWZ(ar)));
#pragma unroll
            for (int nj = 0; nj < 16; nj++) {
                int wr = nj * 16 + ln;
                bf16x8 bf = *(bf16x8*)(wb1 + ((wr * 64 + g * 16) ^ SWZ(wr)));
                a1[nj] = __builtin_amdgcn_mfma_f32_16x16x32_bf16(af, bf, a1[nj], 0, 0, 0);
            }
        }
        __syncthreads();
#pragma unroll
        for (int nj = 0; nj < 16; nj++)
#pragma unroll
            for (int r = 0; r < 4; r++) {
                int row = wv * 16 + g * 4 + r, col = nj * 16 + ln;
                *(unsigned short*)(ihb + ((row * 512 + col * 2) ^ SWZ(row))) =
                    f2bf(a1[nj][r]);
            }
    }
    __syncthreads();

    if (colh == 0) {
        f32x4 a2[16];
#pragma unroll
        for (int i = 0; i < 16; i++) a2[i] = (f32x4){0.f, 0.f, 0.f, 0.f};
        for (int kc = 0; kc < 256; kc += 32) {
            __syncthreads();
#pragma unroll
            for (int p = 0; p < 4; p++) {
                int r = p * 64 + sr;
                *(bf16x8*)(wb2 + ((r * 64 + sc * 2) ^ SWZ(r))) =
                    *(const bf16x8*)(wkv_bf + (long)r * 256 + kc + sc);
            }
            __syncthreads();
            int row = wv * 16 + ln;
            bf16x8 af = *(bf16x8*)(ihb + ((row * 512 + (kc + g * 8) * 2) ^ SWZ(row)));
#pragma unroll
            for (int nj = 0; nj < 16; nj++) {
                int wr = nj * 16 + ln;
                bf16x8 bf = *(bf16x8*)(wb2 + ((wr * 64 + g * 16) ^ SWZ(wr)));
                a2[nj] = __builtin_amdgcn_mfma_f32_16x16x32_bf16(af, bf, a2[nj], 0, 0, 0);
            }
        }
#pragma unroll
        for (int nj = 0; nj < 16; nj++)
#pragma unroll
            for (int r = 0; r < 4; r++) {
                int R = rg * 64 + wv * 16 + g * 4 + r, n = nj * 16 + ln;
                Kbuf[(long)R * 256 + n] = f2bf(a2[nj][r] + beff[256 + n]);
            }
    } else {
        const unsigned short* wp = wkv_bf + 65536;
        f32x4 a2[16];
#pragma unroll
        for (int i = 0; i < 16; i++) a2[i] = (f32x4){0.f, 0.f, 0.f, 0.f};
        for (int kc = 0; kc < 256; kc += 32) {
            __syncthreads();
#pragma unroll
            for (int p = 0; p < 4; p++) {
                int r = p * 64 + sr;
                *(bf16x8*)(wb2 + ((r * 64 + sc * 2) ^ SWZ(r))) =
                    *(const bf16x8*)(wp + (long)r * 256 + kc + sc);
            }
            __syncthreads();
#pragma unroll
            for (int mi = 0; mi < 4; mi++) {
                int arow = wv * 64 + mi * 16 + ln;
                bf16x8 af = *(bf16x8*)(wb2 + ((arow * 64 + g * 16) ^ SWZ(arow)));
#pragma unroll
                for (int t4 = 0; t4 < 4; t4++) {
                    int brow = t4 * 16 + ln;
                    bf16x8 bfr = *(bf16x8*)(ihb + ((brow * 512 + (kc + g * 8) * 2) ^ SWZ(brow)));
                    a2[mi * 4 + t4] = __builtin_amdgcn_mfma_f32_16x16x32_bf16(af, bfr, a2[mi * 4 + t4], 0, 0, 0);
                }
            }
        }
#pragma unroll
        for (int mi = 0; mi < 4; mi++)
#pragma unroll
            for (int t4 = 0; t4 < 4; t4++)
#pragma unroll
                for (int r = 0; r < 4; r++) {
                    int nrow = wv * 64 + mi * 16 + g * 4 + r;
                    VTg[(long)nrow * 512 + rg * 64 + t4 * 16 + ln] =
                        f2bf(a2[mi * 4 + t4][r] + beff[512 + nrow]);
                }
    }
}

// ---------------------------------------------------------------------------
// megattn (round-20 verbatim, measured 53.9 us).
// ---------------------------------------------------------------------------
__global__ __launch_bounds__(256, 2) void megattn(
    const float* __restrict__ company_x,
    const unsigned short* __restrict__ Wcq,
    const float* __restrict__ beff,
    const unsigned short* __restrict__ Kbuf,
    const unsigned short* __restrict__ VTg,
    const float* __restrict__ ctgt,
    const unsigned short* __restrict__ wout,
    const float* __restrict__ b_out,
    const int* __restrict__ list, const int* __restrict__ nlist,
    float* __restrict__ pooled)
{
    const int M = *nlist;
    const int bm = blockIdx.x * 16;
    if (bm >= M) return;

    __shared__ char lds[32768];
    const int t = threadIdx.x, h = t >> 6, lane = t & 63;
    const int g = lane >> 4, ln = lane & 15;
    char* qbase = lds + h * 2048;
    char* xbase = lds + 8192;
    char* pbase = lds + 16384 + h * 4096;

    {
        int row = t >> 4, c0 = (t & 15) * 16;
        int mr = bm + row; if (mr > M - 1) mr = M - 1;
        const float* src = company_x + (long)list[mr] * 256 + c0;
        *(bf16x8*)(xbase + ((row * 512 + c0 * 2) ^ SWZ(row))) = cvt8r(src);
        *(bf16x8*)(xbase + ((row * 512 + c0 * 2 + 16) ^ SWZ(row))) = cvt8r(src + 8);
    }
    __syncthreads();

    bf16x8 qf0, qf1;
    {
        f32x4 qa[4];
#pragma unroll
        for (int i = 0; i < 4; i++) qa[i] = (f32x4){0.f, 0.f, 0.f, 0.f};
#pragma unroll
        for (int kc = 0; kc < 256; kc += 32) {
            bf16x8 af = *(bf16x8*)(xbase + ((ln * 512 + (kc + g * 8) * 2) ^ SWZ(ln)));
#pragma unroll
            for (int nj = 0; nj < 4; nj++) {
                bf16x8 bf = *(const bf16x8*)(Wcq + (long)(h * 64 + nj * 16 + ln) * 256 + kc + g * 8);
                qa[nj] = __builtin_amdgcn_mfma_f32_16x16x32_bf16(af, bf, qa[nj], 0, 0, 0);
            }
        }
#pragma unroll
        for (int nj = 0; nj < 4; nj++)
#pragma unroll
            for (int r = 0; r < 4; r++) {
                int row = g * 4 + r, col = nj * 16 + ln;
                *(unsigned short*)(qbase + ((row * 128 + col * 2) ^ SWZ(row))) =
                    f2bf((qa[nj][r] + beff[h * 64 + col]) * 0.125f);
            }
        qf0 = *(bf16x8*)(qbase + ((ln * 128 + g * 16) ^ SWZ(ln)));
        qf1 = *(bf16x8*)(qbase + ((ln * 128 + 64 + g * 16) ^ SWZ(ln)));
    }

    f32x4 acc[4];
#pragma unroll
    for (int i = 0; i < 4; i++) acc[i] = (f32x4){0.f, 0.f, 0.f, 0.f};
    float mreg[4] = {-1e30f, -1e30f, -1e30f, -1e30f};
    float lreg[4] = {0.f, 0.f, 0.f, 0.f};

#pragma unroll
    for (int tile = 0; tile < 2; tile++) {
        float cnt[16];
#pragma unroll
        for (int j = 0; j < 16; j++)
            cnt[j] = ctgt[tile * 256 + (j >> 1) * 32 + (j & 1) * 16 + ln];

        f32x4 S[8][2];
#pragma unroll
        for (int half = 0; half < 2; half++) {
            bf16x8 k0r[4][2], k1r[4][2];
#pragma unroll
            for (int c4 = 0; c4 < 4; c4++)
#pragma unroll
                for (int sub = 0; sub < 2; sub++) {
                    const unsigned short* kr = Kbuf +
                        (long)(tile * 256 + (half * 4 + c4) * 32 + sub * 16 + ln) * 256 + h * 64 + g * 8;
                    k0r[c4][sub] = *(const bf16x8*)(kr);
                    k1r[c4][sub] = *(const bf16x8*)(kr + 32);
                }
#pragma unroll
            for (int c4 = 0; c4 < 4; c4++)
#pragma unroll
                for (int sub = 0; sub < 2; sub++) {
                    f32x4 s = (f32x4){0.f, 0.f, 0.f, 0.f};
                    s = __builtin_amdgcn_mfma_f32_16x16x32_bf16(qf0, k0r[c4][sub], s, 0, 0, 0);
                    s = __builtin_amdgcn_mfma_f32_16x16x32_bf16(qf1, k1r[c4][sub], s, 0, 0, 0);
                    S[half * 4 + c4][sub] = s;
                }
        }

        bf16x8 vr[2][2][4];
#pragma unroll
        for (int j = 0; j < 2; j++)
#pragma unroll
            for (int t4 = 0; t4 < 4; t4++)
                vr[0][j][t4] = *(const bf16x8*)(
                    VTg + (long)(h * 64 + t4 * 16 + ln) * 512 + tile * 256 + j * 32 + g * 8);

        float tm[4] = {-1e30f, -1e30f, -1e30f, -1e30f};
#pragma unroll
        for (int c = 0; c < 8; c++)
#pragma unroll
            for (int sub = 0; sub < 2; sub++)
#pragma unroll
                for (int r = 0; r < 4; r++) tm[r] = fmaxf(tm[r], S[c][sub][r]);
#pragma unroll
        for (int st = 1; st < 16; st <<= 1)
#pragma unroll
            for (int r = 0; r < 4; r++) tm[r] = fmaxf(tm[r], __shfl_xor(tm[r], st));

        float corr[4];
#pragma unroll
        for (int r = 0; r < 4; r++) {
            float mn = fmaxf(mreg[r], tm[r]);
            corr[r] = __expf(mreg[r] - mn);
            mreg[r] = mn;
        }

        float ps[4] = {0.f, 0.f, 0.f, 0.f};
#pragma unroll
        for (int c = 0; c < 8; c++)
#pragma unroll
            for (int sub = 0; sub < 2; sub++) {
                float cv = cnt[c * 2 + sub];
#pragma unroll
                for (int r = 0; r < 4; r++) {
                    float p = cv * __expf(S[c][sub][r] - mreg[r]);
                    S[c][sub][r] = p;
                    ps[r] += p;
                }
            }
#pragma unroll
        for (int st = 1; st < 16; st <<= 1)
#pragma unroll
            for (int r = 0; r < 4; r++) ps[r] += __shfl_xor(ps[r], st);
#pragma unroll
        for (int r = 0; r < 4; r++) lreg[r] = lreg[r] * corr[r] + ps[r];
#pragma unroll
        for (int i = 0; i < 4; i++)
#pragma unroll
            for (int r = 0; r < 4; r++) acc[i][r] *= corr[r];

#pragma unroll
        for (int grp = 0; grp < 4; grp++) {
            if (grp < 3) {
#pragma unroll
                for (int j = 0; j < 2; j++)
#pragma unroll
                    for (int t4 = 0; t4 < 4; t4++)
                        vr[(grp + 1) & 1][j][t4] = *(const bf16x8*)(
                            VTg + (long)(h * 64 + t4 * 16 + ln) * 512 +
                            tile * 256 + ((grp + 1) * 2 + j) * 32 + g * 8);
            }
#pragma unroll
            for (int j = 0; j < 2; j++) {
                int c = grp * 2 + j;
                char* pb = pbase + (c & 3) * 1024;
#pragma unroll
                for (int sub = 0; sub < 2; sub++)
#pragma unroll
                    for (int r = 0; r < 4; r++) {
                        int row = g * 4 + r;
                        *(unsigned short*)(pb + ((row * 64 + (sub * 16 + ln) * 2) ^ SWZ4(row))) =
                            f2bf(S[c][sub][r]);
                    }
                bf16x8 pa = *(bf16x8*)(pb + ((ln * 64 + g * 16) ^ SWZ4(ln)));
#pragma unroll
                for (int t4 = 0; t4 < 4; t4++)
                    acc[t4] = __builtin_amdgcn_mfma_f32_16x16x32_bf16(
                        pa, vr[grp & 1][j][t4], acc[t4], 0, 0, 0);
            }
        }
    }

#pragma unroll
    for (int t4 = 0; t4 < 4; t4++)
#pragma unroll
        for (int r = 0; r < 4; r++) {
            int row = g * 4 + r, col = t4 * 16 + ln;
            *(unsigned short*)(qbase + ((row * 128 + col * 2) ^ SWZ(row))) =
                f2bf(acc[t4][r] / lreg[r]);
        }
    __syncthreads();

    {
        f32x4 oa[4];
#pragma unroll
        for (int i = 0; i < 4; i++) oa[i] = (f32x4){0.f, 0.f, 0.f, 0.f};
#pragma unroll
        for (int kc = 0; kc < 256; kc += 32) {
            int hs = kc >> 6;
            int off = (kc & 63) + g * 8;
            bf16x8 af = *(bf16x8*)(lds + hs * 2048 + ((ln * 128 + off * 2) ^ SWZ(ln)));
#pragma unroll
            for (int nj = 0; nj < 4; nj++) {
                bf16x8 bf = *(const bf16x8*)(wout + (long)(h * 64 + nj * 16 + ln) * 256 + kc + g * 8);
                oa[nj] = __builtin_amdgcn_mfma_f32_16x16x32_bf16(af, bf, oa[nj], 0, 0, 0);
            }
        }
#pragma unroll
        for (int nj = 0; nj < 4; nj++) {
            int n = h * 64 + nj * 16 + ln;
            float bv = b_out[n];
#pragma unroll
            for (int r = 0; r < 4; r++) {
                int R = bm + g * 4 + r;
                if (R < M)
                    pooled[(long)list[R] * 256 + n] = oa[nj][r] + bv;
            }
        }
    }
}

// ---------------------------------------------------------------------------
// gemm_ln (round-13 verbatim): company GEMM + residual + pooled + LN.
// ---------------------------------------------------------------------------
__global__ __launch_bounds__(256) void gemm_ln(
    const float* __restrict__ A, const unsigned short* __restrict__ W,
    const float* __restrict__ bias,
    const float* __restrict__ pooled, const float* __restrict__ csrc,
    const float* __restrict__ gamma, const float* __restrict__ beta,
    float* __restrict__ out, int M, int K)
{
    __shared__ unsigned short As[64 * 32];
    __shared__ unsigned short Ws[256 * 32];
    char* abase = (char*)As;
    char* wbase = (char*)Ws;

    const int bm = blockIdx.x * 64;
    const int t = threadIdx.x;
    const int wv = t >> 6, lane = t & 63, g = lane >> 4, ln = lane & 15;

    f32x4 acc[16];
#pragma unroll
    for (int i = 0; i < 16; i++) acc[i] = (f32x4){0.f, 0.f, 0.f, 0.f};

    const int sr = t >> 2;
    const int sc = (t & 3) * 8;
    int arow = bm + sr; if (arow > M - 1) arow = M - 1;
    const float* aptr = A + (long)arow * K + sc;

    for (int kc = 0; kc < K; kc += 32) {
        __syncthreads();
        stage_f32(aptr + kc, abase, sr, sc);
#pragma unroll
        for (int p = 0; p < 4; p++) {
            int r = p * 64 + sr;
            *(bf16x8*)(wbase + ((r * 64 + sc * 2) ^ SWZ(r))) =
                *(const bf16x8*)(W + (long)r * K + kc + sc);
        }
        __syncthreads();

        const int ar = wv * 16 + ln;
        bf16x8 af = *(bf16x8*)(abase + ((ar * 64 + g * 16) ^ SWZ(ar)));
#pragma unroll
        for (int nj = 0; nj < 16; nj++) {
            int wr = nj * 16 + ln;
            bf16x8 bf = *(bf16x8*)(wbase + ((wr * 64 + g * 16) ^ SWZ(wr)));
            acc[nj] = __builtin_amdgcn_mfma_f32_16x16x32_bf16(af, bf, acc[nj], 0, 0, 0);
        }
    }

#pragma unroll
    for (int r = 0; r < 4; r++) {
        int R = bm + wv * 16 + g * 4 + r;
        bool valid = R < M;
        int Rc = valid ? R : 0;
        float cntv = csrc[Rc];
        float factor = (valid && cntv > 0.f) ? cntv / (cntv + 1e-6f) : 0.f;

        float v[16];
        float sum = 0.f, sq = 0.f;
#pragma unroll
        for (int nj = 0; nj < 16; nj++) {
            int n = nj * 16 + ln;
            float x = acc[nj][r] + bias[n] + factor * pooled[(long)Rc * 256 + n];
            v[nj] = x;
            sum += x;
            sq  += x * x;
        }
#pragma unroll
        for (int st = 1; st < 16; st <<= 1) {
            sum += __shfl_xor(sum, st);
            sq  += __shfl_xor(sq,  st);
        }
        float mean = sum * (1.0f / 256.0f);
        float var  = sq * (1.0f / 256.0f) - mean * mean;
        float rstd = rsqrtf(var + 1e-5f);
        if (valid) {
#pragma unroll
            for (int nj = 0; nj < 16; nj++) {
                int n = nj * 16 + ln;
                out[(long)R * 256 + n] = (v[nj] - mean) * rstd * gamma[n] + beta[n];
            }
        }
    }
}

// ---------------------------------------------------------------------------
extern "C" void kernel_launch(void* const* d_in, const int* in_sizes, int n_in,
                              void* d_out, int out_size, void* d_ws, size_t ws_size,
                              hipStream_t stream)
{
    const float* company_x  = (const float*)d_in[0];
    const float* industry_x = (const float*)d_in[1];
    const int*   edge       = (const int*)d_in[2];
    const float* Wc         = (const float*)d_in[3];
    const float* bc         = (const float*)d_in[4];
    const float* Wi         = (const float*)d_in[5];
    const float* bi         = (const float*)d_in[6];
    const float* w_in       = (const float*)d_in[7];
    const float* b_in       = (const float*)d_in[8];
    const float* w_out      = (const float*)d_in[9];
    const float* b_out      = (const float*)d_in[10];
    const float* gamma      = (const float*)d_in[11];
    const float* beta       = (const float*)d_in[12];
    float* out = (float*)d_out;

    const int* src = edge;
    const int* tgt = edge + E_EDGES;

    // workspace carve (float units)
    float* wf = (float*)d_ws;
    size_t o = 0;
    unsigned short* Wc_bf   = (unsigned short*)(wf + o); o += 32768;  // 256x256
    unsigned short* wout_bf = (unsigned short*)(wf + o); o += 32768;
    unsigned short* WcT_bf  = (unsigned short*)(wf + o); o += 32768;
    unsigned short* Wi_bf   = (unsigned short*)(wf + o); o += 16384;  // 256x128
    unsigned short* wkv_bf  = (unsigned short*)(wf + o); o += 65536;  // 512x256
    unsigned short* Wcq_bf  = (unsigned short*)(wf + o); o += 32768;
    unsigned short* Kbuf    = (unsigned short*)(wf + o); o += 65536;  // 512x256
    unsigned short* VTg     = (unsigned short*)(wf + o); o += 65536;  // 256x512
    float* pooled           = wf + o; o += (size_t)N_COMP * 256;
    float* beff             = wf + o; o += 768;
    int*   list             = (int*)(wf + o); o += E_EDGES;
    // zero region: csrc | ctgt | nlist | flags (zeroed by prepZ)
    float* zregion          = wf + o;
    float* csrc             = wf + o; o += N_COMP;
    float* ctgt             = wf + o; o += NKEYS;
    int*   nlist            = (int*)(wf + o); o += 4;
    int*   flags            = (int*)(wf + o); o += N_COMP;

    prepZ<<<dim3(228), dim3(256), 0, stream>>>(
        Wc, Wi, w_out, w_in, bc, bi, b_in,
        zregion, Wc_bf, wout_bf, WcT_bf, Wi_bf, wkv_bf, beff);

    fusedWB<<<dim3(52), dim3(256), 0, stream>>>(
        w_in, WcT_bf, industry_x, Wi_bf, wkv_bf, beff,
        src, tgt, csrc, ctgt, flags, nlist, list,
        Wcq_bf, Kbuf, VTg);

    megattn<<<dim3(512), dim3(256), 0, stream>>>(
        company_x, Wcq_bf, beff, Kbuf, VTg, ctgt, wout_bf, b_out,
        list, nlist, pooled);

    gemm_ln<<<dim3((N_COMP + 63) / 64), dim3(256), 0, stream>>>(
        company_x, Wc_bf, bc, pooled, csrc, gamma, beta, out, N_COMP, 256);
}